// Round 4
// baseline (3514.235 us; speedup 1.0000x reference)
//
#include <hip/hip_runtime.h>
#include <hip/hip_bf16.h>
#include <cstdint>

// Problem constants (match reference)
#define M_TOK 8192
#define K_IN  4096
#define N_OUT 11008
#define NP8   (N_OUT / 8)   // 1376 packed int32 per row of qweight
#define GS    128           // quant group size

typedef __attribute__((ext_vector_type(8))) short  s16x8;
typedef __attribute__((ext_vector_type(8))) __bf16 bf16x8;
typedef __attribute__((ext_vector_type(4))) float  f32x4;

// ---------------------------------------------------------------------------
// Fully fused W4A16 GEMM: C = x * dequant(qw) + bias.  NO workspace.
//
// DTYPE CONTRACT (deduced round 3): harness materializes the reference's
// float16 arrays as FLOAT32 on device (out_npz 210MB > 180MB raw fp16; spec
// says non-bf16 float -> float*). So x/scales/bias/out are float*, qw/qz int32.
//
// 128x128 tile, BK=64, 4 waves (2x2), mfma_f32_16x16x32_bf16.
// A: reg-staged f32 -> bf16 convert -> ds_write_b128.
// B: int4 dequant in-register -> bf16 -> ds_write_b128 (K-major W^T tile).
// Both LDS tiles XOR-swizzled: physical 16B chunk p of row r holds logical
// chunk p ^ (r & 7); applied identically on write and read.
// ---------------------------------------------------------------------------
__global__ __launch_bounds__(256) void fused_w4a16_kernel(
    const float*        __restrict__ A,     // x [M][K] f32
    const unsigned int* __restrict__ qw,    // [K][N/8]
    const unsigned int* __restrict__ qz,    // [K/GS][N/8]
    const float*        __restrict__ sc,    // [K/GS][N] f32
    const float*        __restrict__ bias,  // [N] f32
    float*              __restrict__ C)     // [M][N] f32
{
    __shared__ __align__(16) unsigned short As[128 * 64];
    __shared__ __align__(16) unsigned short Bs[128 * 64];

    const int tid = threadIdx.x;
    const int l   = tid & 63;
    const int w   = tid >> 6;       // wave 0..3
    const int wm  = w >> 1;         // wave row (2)
    const int wn  = w & 1;          // wave col (2)
    const size_t blockM = (size_t)blockIdx.x * 128;
    const int    colN   = blockIdx.y * 128;   // global output-column base

    const float* Ag = A + blockM * K_IN;

    // ---- A staging roles: 8 lanes/row, 8-elem (32B f32) chunk, 4 rows/thread
    const int r_in = l >> 3;        // row within an 8-row span (== row & 7)
    const int cch  = l & 7;         // logical k-chunk this lane fetches
    int    aw_off[4];
    size_t ag_off[4];
#pragma unroll
    for (int qq = 0; qq < 4; qq++) {
        const int row = w * 32 + qq * 8 + r_in;
        aw_off[qq] = row * 64 + ((cch ^ r_in) * 8);
        ag_off[qq] = (size_t)row * K_IN + cch * 8;
    }

    // ---- B dequant roles: 4 chunks/thread; chunk = p*256+tid ----
    const int kc = tid & 7;         // logical k-chunk (8 k-elements)
    int ngl[4];     // global output column
    int j8[4];      // packed-word index
    int shn[4];     // nibble shift
    int bs_off[4];  // swizzled LDS write offset (elements)
#pragma unroll
    for (int p = 0; p < 4; p++) {
        const int nl = p * 32 + (tid >> 3);
        const int ng = colN + nl;
        ngl[p]    = ng;
        j8[p]     = ng >> 3;
        shn[p]    = 4 * (ng & 7);
        bs_off[p] = nl * 64 + ((kc ^ (nl & 7)) * 8);
    }

    f32x4 acc[4][4];
#pragma unroll
    for (int i = 0; i < 4; i++)
#pragma unroll
        for (int j = 0; j < 4; j++) acc[i][j] = (f32x4){0.f, 0.f, 0.f, 0.f};

    const int lrow = l & 15;
    const int lk   = l >> 4;        // 0..3
    const int NT   = K_IN / 64;

    for (int kt = 0; kt < NT; ++kt) {
        const int K0 = kt * 64;
        const int g  = K0 >> 7;     // quant group (GS=128, BK=64)

        // ---- issue A loads (f32) ----
        float4 fa[4][2];
#pragma unroll
        for (int qq = 0; qq < 4; qq++) {
            fa[qq][0] = *(const float4*)(Ag + ag_off[qq] + K0);
            fa[qq][1] = *(const float4*)(Ag + ag_off[qq] + K0 + 4);
        }

        // ---- issue B packed loads + per-chunk zero/scale ----
        unsigned int q[4][8];
        float sf[4], nzs[4];
#pragma unroll
        for (int p = 0; p < 4; p++) {
            const unsigned int* qp = qw + (size_t)(K0 + kc * 8) * NP8 + j8[p];
#pragma unroll
            for (int i = 0; i < 8; i++) q[p][i] = qp[(size_t)i * NP8];
            const float zf = (float)((qz[(size_t)g * NP8 + j8[p]] >> shn[p]) & 0xFu);
            sf[p]  = sc[(size_t)g * N_OUT + ngl[p]];
            nzs[p] = -zf * sf[p];
        }

        __syncthreads();            // all waves done READING previous tile

#pragma unroll
        for (int qq = 0; qq < 4; qq++) {
            bf16x8 h;
#pragma unroll
            for (int i = 0; i < 4; i++) {
                h[i]     = (__bf16)(((const float*)&fa[qq][0])[i]);
                h[i + 4] = (__bf16)(((const float*)&fa[qq][1])[i]);
            }
            *(int4*)&As[aw_off[qq]] = __builtin_bit_cast(int4, h);
        }
#pragma unroll
        for (int p = 0; p < 4; p++) {
            bf16x8 h;
#pragma unroll
            for (int i = 0; i < 8; i++) {
                const float nib = (float)((q[p][i] >> shn[p]) & 0xFu);
                h[i] = (__bf16)fmaf(nib, sf[p], nzs[p]);
            }
            *(int4*)&Bs[bs_off[p]] = __builtin_bit_cast(int4, h);
        }

        __syncthreads();            // writes visible to all waves

#pragma unroll
        for (int ks = 0; ks < 2; ++ks) {
            s16x8 a[4], b[4];
            const int kcc = ks * 4 + lk;   // logical 16B chunk 0..7
#pragma unroll
            for (int mi = 0; mi < 4; mi++) {
                const int row = wm * 64 + mi * 16 + lrow;
                a[mi] = *(const s16x8*)&As[row * 64 + ((kcc ^ (row & 7)) * 8)];
            }
#pragma unroll
            for (int ni = 0; ni < 4; ni++) {
                const int row = wn * 64 + ni * 16 + lrow;
                b[ni] = *(const s16x8*)&Bs[row * 64 + ((kcc ^ (row & 7)) * 8)];
            }
#pragma unroll
            for (int mi = 0; mi < 4; mi++)
#pragma unroll
                for (int ni = 0; ni < 4; ni++)
                    acc[mi][ni] = __builtin_amdgcn_mfma_f32_16x16x32_bf16(
                        __builtin_bit_cast(bf16x8, a[mi]),
                        __builtin_bit_cast(bf16x8, b[ni]),
                        acc[mi][ni], 0, 0, 0);
        }
    }

    // Epilogue: C/D layout col = lane&15, row = (lane>>4)*4 + reg (m89-verified)
#pragma unroll
    for (int ni = 0; ni < 4; ++ni) {
        const int ng = colN + wn * 64 + ni * 16 + lrow;
        const float bv = bias[ng];
#pragma unroll
        for (int mi = 0; mi < 4; ++mi) {
            f32x4 v = acc[mi][ni];
#pragma unroll
            for (int r = 0; r < 4; r++) {
                const size_t grow = blockM + wm * 64 + mi * 16 + lk * 4 + r;
                C[grow * N_OUT + ng] = v[r] + bv;
            }
        }
    }
}

// ---------------------------------------------------------------------------
extern "C" void kernel_launch(void* const* d_in, const int* in_sizes, int n_in,
                              void* d_out, int out_size, void* d_ws, size_t ws_size,
                              hipStream_t stream)
{
    const float*        x    = (const float*)d_in[0];
    const unsigned int* qw   = (const unsigned int*)d_in[1];
    const unsigned int* qz   = (const unsigned int*)d_in[2];
    const float*        sc   = (const float*)d_in[3];
    const float*        bias = (const float*)d_in[4];
    float*              out  = (float*)d_out;
    (void)d_ws; (void)ws_size;   // no workspace

    dim3 grid(M_TOK / 128, N_OUT / 128);
    fused_w4a16_kernel<<<grid, 256, 0, stream>>>(x, qw, qz, sc, bias, out);
}

// Round 6
// 3452.550 us; speedup vs baseline: 1.0179x; 1.0179x over previous
//
#include <hip/hip_runtime.h>
#include <hip/hip_bf16.h>
#include <cstdint>

// Problem constants (match reference)
#define M_TOK 8192
#define K_IN  4096
#define N_OUT 11008
#define NP8   (N_OUT / 8)   // 1376 packed int32 per row of qweight
#define GS    128           // quant group size

// DTYPE CONTRACT (verified round 4): x/scales/bias/out are float32 on device;
// qweight/qzeros are int32.

typedef __attribute__((ext_vector_type(8))) short  s16x8;
typedef __attribute__((ext_vector_type(8))) __bf16 bf16x8;
typedef __attribute__((ext_vector_type(4))) float  f32x4;

// ---------------------------------------------------------------------------
// x f32 -> bf16, grid-strided, 8 elems/thread/iter.
// ---------------------------------------------------------------------------
__global__ __launch_bounds__(256) void convert_x_kernel(
    const float* __restrict__ in, unsigned short* __restrict__ outp, long n8)
{
    long i = (long)blockIdx.x * blockDim.x + threadIdx.x;
    const long stride = (long)gridDim.x * blockDim.x;
    for (; i < n8; i += stride) {
        const float4 a = ((const float4*)in)[2 * i];
        const float4 b = ((const float4*)in)[2 * i + 1];
        bf16x8 h;
        h[0] = (__bf16)a.x; h[1] = (__bf16)a.y; h[2] = (__bf16)a.z; h[3] = (__bf16)a.w;
        h[4] = (__bf16)b.x; h[5] = (__bf16)b.y; h[6] = (__bf16)b.z; h[7] = (__bf16)b.w;
        ((int4*)outp)[i] = __builtin_bit_cast(int4, h);
    }
}

// ---------------------------------------------------------------------------
// Dequant int4 -> bf16 W^T [nc][K] (chunk-local) into workspace.
// Thread: 8k x 8n block. Block: 128k (one group) x 128n. grid=(K/GS, nc/128).
// ---------------------------------------------------------------------------
__global__ __launch_bounds__(256) void dequant_kernel(
    const unsigned int* __restrict__ qw,    // [K][N/8]
    const unsigned int* __restrict__ qz,    // [K/GS][N/8]
    const float*        __restrict__ sc,    // [K/GS][N] f32
    unsigned short*     __restrict__ wt,    // out: [nc][K] bf16 bits
    int n_base)
{
    const int tid = threadIdx.x;
    const int k8  = tid & 15;        // fast dim -> coalesced 16B stores along K
    const int n8  = tid >> 4;
    const int g   = blockIdx.x;      // k-block == quant group (both 128)
    const int k0  = g * GS + k8 * 8;
    const int ncl = blockIdx.y * 128 + n8 * 8;  // chunk-local column base
    const int ng  = n_base + ncl;               // global output column
    const int j8  = ng >> 3;

    const unsigned int z = qz[(size_t)g * NP8 + j8];

    float s[8];
    *(float4*)&s[0] = *(const float4*)&sc[(size_t)g * N_OUT + ng];
    *(float4*)&s[4] = *(const float4*)&sc[(size_t)g * N_OUT + ng + 4];

    unsigned int q[8];
#pragma unroll
    for (int i = 0; i < 8; i++) q[i] = qw[(size_t)(k0 + i) * NP8 + j8];

#pragma unroll
    for (int t = 0; t < 8; t++) {
        const float sf  = s[t];
        const float nzs = -(float)((z >> (4 * t)) & 0xFu) * sf;
        bf16x8 h;
#pragma unroll
        for (int i = 0; i < 8; i++) {
            const float nib = (float)((q[i] >> (4 * t)) & 0xFu);
            h[i] = (__bf16)fmaf(nib, sf, nzs);
        }
        *(int4*)&wt[(size_t)(ncl + t) * K_IN + k0] = __builtin_bit_cast(int4, h);
    }
}

// ---------------------------------------------------------------------------
// bf16 GEMM: C = A * Bt^T + bias.  AMODE 0: A is bf16 ws [M][K];
// AMODE 1: A is f32 x [M][K], converted during staging (proven in r4).
// 128x128 tile, BK=64, 4 waves (2x2), mfma_f32_16x16x32_bf16, reg-staged,
// XOR-swizzled LDS (chunk p of row r holds logical chunk p^(r&7)).
// ---------------------------------------------------------------------------
template <int AMODE>
__global__ __launch_bounds__(256) void gemm_bt_kernel(
    const void*           __restrict__ Av,    // bf16 ws or f32 x, [M][K]
    const unsigned short* __restrict__ Bt,    // wt chunk [nc][K] bf16
    const float*          __restrict__ bias,  // [N] f32
    float*                __restrict__ C,     // [M][N] f32
    int n_base)
{
    __shared__ __align__(16) unsigned short As[128 * 64];
    __shared__ __align__(16) unsigned short Bs[128 * 64];

    const int tid = threadIdx.x;
    const int l   = tid & 63;
    const int w   = tid >> 6;
    const int wm  = w >> 1;
    const int wn  = w & 1;
    const size_t blockM = (size_t)blockIdx.x * 128;
    const int    colc   = blockIdx.y * 128;   // chunk-local col base

    const unsigned short* Agb = (const unsigned short*)Av + blockM * K_IN;
    const float*          Agf = (const float*)Av + blockM * K_IN;
    const unsigned short* Bg  = Bt + (size_t)colc * K_IN;

    const int r_in = l >> 3;
    const int cch  = l & 7;
    int    lw_off[4];
    size_t g_off[4];
#pragma unroll
    for (int qq = 0; qq < 4; qq++) {
        const int row = w * 32 + qq * 8 + r_in;
        lw_off[qq] = row * 64 + ((cch ^ r_in) * 8);
        g_off[qq]  = (size_t)row * K_IN + cch * 8;
    }

    f32x4 acc[4][4];
#pragma unroll
    for (int i = 0; i < 4; i++)
#pragma unroll
        for (int j = 0; j < 4; j++) acc[i][j] = (f32x4){0.f, 0.f, 0.f, 0.f};

    const int lrow = l & 15;
    const int lk   = l >> 4;
    const int NT   = K_IN / 64;

    for (int kt = 0; kt < NT; ++kt) {
        const int K0 = kt * 64;

        int4   ra[4], rb[4];
        float4 fa[4][2];
        if (AMODE == 0) {
#pragma unroll
            for (int qq = 0; qq < 4; qq++)
                ra[qq] = *(const int4*)(Agb + g_off[qq] + K0);
        } else {
#pragma unroll
            for (int qq = 0; qq < 4; qq++) {
                fa[qq][0] = *(const float4*)(Agf + g_off[qq] + K0);
                fa[qq][1] = *(const float4*)(Agf + g_off[qq] + K0 + 4);
            }
        }
#pragma unroll
        for (int qq = 0; qq < 4; qq++)
            rb[qq] = *(const int4*)(Bg + g_off[qq] + K0);

        __syncthreads();            // all waves done READING previous tile

        if (AMODE == 1) {
#pragma unroll
            for (int qq = 0; qq < 4; qq++) {
                bf16x8 h;
#pragma unroll
                for (int i = 0; i < 4; i++) {
                    h[i]     = (__bf16)(((const float*)&fa[qq][0])[i]);
                    h[i + 4] = (__bf16)(((const float*)&fa[qq][1])[i]);
                }
                ra[qq] = __builtin_bit_cast(int4, h);
            }
        }
#pragma unroll
        for (int qq = 0; qq < 4; qq++) *(int4*)&As[lw_off[qq]] = ra[qq];
#pragma unroll
        for (int qq = 0; qq < 4; qq++) *(int4*)&Bs[lw_off[qq]] = rb[qq];

        __syncthreads();            // writes visible

#pragma unroll
        for (int ks = 0; ks < 2; ++ks) {
            s16x8 a[4], b[4];
            const int kcc = ks * 4 + lk;
#pragma unroll
            for (int mi = 0; mi < 4; mi++) {
                const int row = wm * 64 + mi * 16 + lrow;
                a[mi] = *(const s16x8*)&As[row * 64 + ((kcc ^ (row & 7)) * 8)];
            }
#pragma unroll
            for (int ni = 0; ni < 4; ni++) {
                const int row = wn * 64 + ni * 16 + lrow;
                b[ni] = *(const s16x8*)&Bs[row * 64 + ((kcc ^ (row & 7)) * 8)];
            }
#pragma unroll
            for (int mi = 0; mi < 4; mi++)
#pragma unroll
                for (int ni = 0; ni < 4; ni++)
                    acc[mi][ni] = __builtin_amdgcn_mfma_f32_16x16x32_bf16(
                        __builtin_bit_cast(bf16x8, a[mi]),
                        __builtin_bit_cast(bf16x8, b[ni]),
                        acc[mi][ni], 0, 0, 0);
        }
    }

    // Epilogue: C/D layout col = lane&15, row = (lane>>4)*4 + reg
#pragma unroll
    for (int ni = 0; ni < 4; ++ni) {
        const int ng = n_base + colc + wn * 64 + ni * 16 + lrow;
        const float bv = bias[ng];
#pragma unroll
        for (int mi = 0; mi < 4; ++mi) {
            f32x4 v = acc[mi][ni];
#pragma unroll
            for (int r = 0; r < 4; r++) {
                const size_t grow = blockM + wm * 64 + mi * 16 + lk * 4 + r;
                C[grow * N_OUT + ng] = v[r] + bv;
            }
        }
    }
}

// ---------------------------------------------------------------------------
// Fallback: fully fused kernel (passed round 4, verbatim).
// ---------------------------------------------------------------------------
__global__ __launch_bounds__(256) void fused_w4a16_kernel(
    const float*        __restrict__ A,
    const unsigned int* __restrict__ qw,
    const unsigned int* __restrict__ qz,
    const float*        __restrict__ sc,
    const float*        __restrict__ bias,
    float*              __restrict__ C)
{
    __shared__ __align__(16) unsigned short As[128 * 64];
    __shared__ __align__(16) unsigned short Bs[128 * 64];

    const int tid = threadIdx.x;
    const int l   = tid & 63;
    const int w   = tid >> 6;
    const int wm  = w >> 1;
    const int wn  = w & 1;
    const size_t blockM = (size_t)blockIdx.x * 128;
    const int    colN   = blockIdx.y * 128;

    const float* Ag = A + blockM * K_IN;

    const int r_in = l >> 3;
    const int cch  = l & 7;
    int    aw_off[4];
    size_t ag_off[4];
#pragma unroll
    for (int qq = 0; qq < 4; qq++) {
        const int row = w * 32 + qq * 8 + r_in;
        aw_off[qq] = row * 64 + ((cch ^ r_in) * 8);
        ag_off[qq] = (size_t)row * K_IN + cch * 8;
    }

    const int kc = tid & 7;
    int ngl[4], j8[4], shn[4], bs_off[4];
#pragma unroll
    for (int p = 0; p < 4; p++) {
        const int nl = p * 32 + (tid >> 3);
        const int ng = colN + nl;
        ngl[p]    = ng;
        j8[p]     = ng >> 3;
        shn[p]    = 4 * (ng & 7);
        bs_off[p] = nl * 64 + ((kc ^ (nl & 7)) * 8);
    }

    f32x4 acc[4][4];
#pragma unroll
    for (int i = 0; i < 4; i++)
#pragma unroll
        for (int j = 0; j < 4; j++) acc[i][j] = (f32x4){0.f, 0.f, 0.f, 0.f};

    const int lrow = l & 15;
    const int lk   = l >> 4;
    const int NT   = K_IN / 64;

    for (int kt = 0; kt < NT; ++kt) {
        const int K0 = kt * 64;
        const int g  = K0 >> 7;

        float4 fa[4][2];
#pragma unroll
        for (int qq = 0; qq < 4; qq++) {
            fa[qq][0] = *(const float4*)(Ag + ag_off[qq] + K0);
            fa[qq][1] = *(const float4*)(Ag + ag_off[qq] + K0 + 4);
        }

        unsigned int q[4][8];
        float sf[4], nzs[4];
#pragma unroll
        for (int p = 0; p < 4; p++) {
            const unsigned int* qp = qw + (size_t)(K0 + kc * 8) * NP8 + j8[p];
#pragma unroll
            for (int i = 0; i < 8; i++) q[p][i] = qp[(size_t)i * NP8];
            const float zf = (float)((qz[(size_t)g * NP8 + j8[p]] >> shn[p]) & 0xFu);
            sf[p]  = sc[(size_t)g * N_OUT + ngl[p]];
            nzs[p] = -zf * sf[p];
        }

        __syncthreads();

#pragma unroll
        for (int qq = 0; qq < 4; qq++) {
            bf16x8 h;
#pragma unroll
            for (int i = 0; i < 4; i++) {
                h[i]     = (__bf16)(((const float*)&fa[qq][0])[i]);
                h[i + 4] = (__bf16)(((const float*)&fa[qq][1])[i]);
            }
            *(int4*)&As[aw_off[qq]] = __builtin_bit_cast(int4, h);
        }
#pragma unroll
        for (int p = 0; p < 4; p++) {
            bf16x8 h;
#pragma unroll
            for (int i = 0; i < 8; i++) {
                const float nib = (float)((q[p][i] >> shn[p]) & 0xFu);
                h[i] = (__bf16)fmaf(nib, sf[p], nzs[p]);
            }
            *(int4*)&Bs[bs_off[p]] = __builtin_bit_cast(int4, h);
        }

        __syncthreads();

#pragma unroll
        for (int ks = 0; ks < 2; ++ks) {
            s16x8 a[4], b[4];
            const int kcc = ks * 4 + lk;
#pragma unroll
            for (int mi = 0; mi < 4; mi++) {
                const int row = wm * 64 + mi * 16 + lrow;
                a[mi] = *(const s16x8*)&As[row * 64 + ((kcc ^ (row & 7)) * 8)];
            }
#pragma unroll
            for (int ni = 0; ni < 4; ni++) {
                const int row = wn * 64 + ni * 16 + lrow;
                b[ni] = *(const s16x8*)&Bs[row * 64 + ((kcc ^ (row & 7)) * 8)];
            }
#pragma unroll
            for (int mi = 0; mi < 4; mi++)
#pragma unroll
                for (int ni = 0; ni < 4; ni++)
                    acc[mi][ni] = __builtin_amdgcn_mfma_f32_16x16x32_bf16(
                        __builtin_bit_cast(bf16x8, a[mi]),
                        __builtin_bit_cast(bf16x8, b[ni]),
                        acc[mi][ni], 0, 0, 0);
        }
    }

#pragma unroll
    for (int ni = 0; ni < 4; ++ni) {
        const int ng = colN + wn * 64 + ni * 16 + lrow;
        const float bv = bias[ng];
#pragma unroll
        for (int mi = 0; mi < 4; ++mi) {
            f32x4 v = acc[mi][ni];
#pragma unroll
            for (int r = 0; r < 4; r++) {
                const size_t grow = blockM + wm * 64 + mi * 16 + lk * 4 + r;
                C[grow * N_OUT + ng] = v[r] + bv;
            }
        }
    }
}

// ---------------------------------------------------------------------------
extern "C" void kernel_launch(void* const* d_in, const int* in_sizes, int n_in,
                              void* d_out, int out_size, void* d_ws, size_t ws_size,
                              hipStream_t stream)
{
    const float*        x    = (const float*)d_in[0];
    const unsigned int* qw   = (const unsigned int*)d_in[1];
    const unsigned int* qz   = (const unsigned int*)d_in[2];
    const float*        sc   = (const float*)d_in[3];
    const float*        bias = (const float*)d_in[4];
    float*              out  = (float*)d_out;

    const size_t XBF    = (size_t)M_TOK * K_IN * 2;   // 64 MiB bf16 x
    const size_t COL128 = (size_t)128 * K_IN * 2;     // 1 MiB per 128 cols of W^T

    if (ws_size >= XBF + COL128) {
        // Tier A: convert x once, chunked dequant + pure-bf16 GEMM.
        unsigned short* xb = (unsigned short*)d_ws;
        unsigned short* wt = (unsigned short*)((char*)d_ws + XBF);
        const long n8 = (long)M_TOK * K_IN / 8;
        convert_x_kernel<<<2048, 256, 0, stream>>>(x, xb, n8);

        size_t chunk_cols = ((ws_size - XBF) / COL128) * 128;
        if (chunk_cols > (size_t)N_OUT) chunk_cols = N_OUT;
        for (int n0 = 0; n0 < N_OUT; n0 += (int)chunk_cols) {
            int nc = N_OUT - n0;
            if (nc > (int)chunk_cols) nc = (int)chunk_cols;
            dequant_kernel<<<dim3(K_IN / GS, nc / 128), 256, 0, stream>>>(qw, qz, sc, wt, n0);
            gemm_bt_kernel<0><<<dim3(M_TOK / 128, nc / 128), 256, 0, stream>>>(
                xb, wt, bias, out, n0);
        }
    } else if (ws_size >= COL128) {
        // Tier B: chunked dequant + GEMM with f32-A staging conversion.
        unsigned short* wt = (unsigned short*)d_ws;
        size_t chunk_cols = (ws_size / COL128) * 128;
        if (chunk_cols > (size_t)N_OUT) chunk_cols = N_OUT;
        for (int n0 = 0; n0 < N_OUT; n0 += (int)chunk_cols) {
            int nc = N_OUT - n0;
            if (nc > (int)chunk_cols) nc = (int)chunk_cols;
            dequant_kernel<<<dim3(K_IN / GS, nc / 128), 256, 0, stream>>>(qw, qz, sc, wt, n0);
            gemm_bt_kernel<1><<<dim3(M_TOK / 128, nc / 128), 256, 0, stream>>>(
                x, wt, bias, out, n0);
        }
    } else {
        // Tier C: fully fused fallback (proven round 4).
        fused_w4a16_kernel<<<dim3(M_TOK / 128, N_OUT / 128), 256, 0, stream>>>(
            x, qw, qz, sc, bias, out);
    }
}

// Round 7
// 1203.553 us; speedup vs baseline: 2.9199x; 2.8686x over previous
//
#include <hip/hip_runtime.h>
#include <hip/hip_bf16.h>
#include <cstdint>

// Problem constants (match reference)
#define M_TOK 8192
#define K_IN  4096
#define N_OUT 11008
#define NP8   (N_OUT / 8)   // 1376 packed int32 per row of qweight
#define GS    128           // quant group size

// DTYPE CONTRACT (verified round 4): x/scales/bias/out are float32 on device;
// qweight/qzeros are int32.

typedef __attribute__((ext_vector_type(8))) short  s16x8;
typedef __attribute__((ext_vector_type(8))) __bf16 bf16x8;
typedef __attribute__((ext_vector_type(4))) float  f32x4;

// ---------------------------------------------------------------------------
// x f32 -> bf16, grid-strided, 8 elems/thread/iter.
// ---------------------------------------------------------------------------
__global__ __launch_bounds__(256) void convert_x_kernel(
    const float* __restrict__ in, unsigned short* __restrict__ outp, long n8)
{
    long i = (long)blockIdx.x * blockDim.x + threadIdx.x;
    const long stride = (long)gridDim.x * blockDim.x;
    for (; i < n8; i += stride) {
        const float4 a = ((const float4*)in)[2 * i];
        const float4 b = ((const float4*)in)[2 * i + 1];
        bf16x8 h;
        h[0] = (__bf16)a.x; h[1] = (__bf16)a.y; h[2] = (__bf16)a.z; h[3] = (__bf16)a.w;
        h[4] = (__bf16)b.x; h[5] = (__bf16)b.y; h[6] = (__bf16)b.z; h[7] = (__bf16)b.w;
        ((int4*)outp)[i] = __builtin_bit_cast(int4, h);
    }
}

// ---------------------------------------------------------------------------
// Dequant int4 -> bf16 W^T [nc][K] (chunk-local) into workspace. (r6-proven)
// ---------------------------------------------------------------------------
__global__ __launch_bounds__(256) void dequant_kernel(
    const unsigned int* __restrict__ qw,    // [K][N/8]
    const unsigned int* __restrict__ qz,    // [K/GS][N/8]
    const float*        __restrict__ sc,    // [K/GS][N] f32
    unsigned short*     __restrict__ wt,    // out: [nc][K] bf16 bits
    int n_base)
{
    const int tid = threadIdx.x;
    const int k8  = tid & 15;
    const int n8  = tid >> 4;
    const int g   = blockIdx.x;
    const int k0  = g * GS + k8 * 8;
    const int ncl = blockIdx.y * 128 + n8 * 8;
    const int ng  = n_base + ncl;
    const int j8  = ng >> 3;

    const unsigned int z = qz[(size_t)g * NP8 + j8];

    float s[8];
    *(float4*)&s[0] = *(const float4*)&sc[(size_t)g * N_OUT + ng];
    *(float4*)&s[4] = *(const float4*)&sc[(size_t)g * N_OUT + ng + 4];

    unsigned int q[8];
#pragma unroll
    for (int i = 0; i < 8; i++) q[i] = qw[(size_t)(k0 + i) * NP8 + j8];

#pragma unroll
    for (int t = 0; t < 8; t++) {
        const float sf  = s[t];
        const float nzs = -(float)((z >> (4 * t)) & 0xFu) * sf;
        bf16x8 h;
#pragma unroll
        for (int i = 0; i < 8; i++) {
            const float nib = (float)((q[i] >> (4 * t)) & 0xFu);
            h[i] = (__bf16)fmaf(nib, sf, nzs);
        }
        *(int4*)&wt[(size_t)(ncl + t) * K_IN + k0] = __builtin_bit_cast(int4, h);
    }
}

// ---------------------------------------------------------------------------
// m97-structure bf16 GEMM: C = A * Bt^T + bias.
// A bf16 [M][K] (ws), Bt bf16 [nc][K] (ws). 128x128 tile, BK=64, 4 waves.
// Staging: global_load_lds width=16, LINEAR LDS (per-lane global gather,
// wave-uniform LDS base + lane*16 — m97/m104 semantics). Bijective XCD
// swizzle (m204) so consecutive resident blocks share the B-panel in L2.
// ---------------------------------------------------------------------------
#define GLOAD16(gp, lp)                                                        \
    __builtin_amdgcn_global_load_lds(                                          \
        (const __attribute__((address_space(1))) void*)(gp),                   \
        (__attribute__((address_space(3))) void*)(lp), 16, 0, 0)

__global__ __launch_bounds__(256) void gemm_m97_kernel(
    const unsigned short* __restrict__ A,     // xb [M][K] bf16
    const unsigned short* __restrict__ Bt,    // wt chunk [nc][K] bf16
    const float*          __restrict__ bias,  // [N] f32
    float*                __restrict__ C,     // [M][N] f32
    int n_base)
{
    __shared__ __align__(16) unsigned short As[128 * 64];
    __shared__ __align__(16) unsigned short Bs[128 * 64];

    const int tid = threadIdx.x;
    const int l   = tid & 63;
    const int w   = tid >> 6;       // wave 0..3
    const int wm  = w >> 1;
    const int wn  = w & 1;

    // --- bijective XCD swizzle (m204): consecutive swz ids share an N-panel
    const int nwg = gridDim.x;           // 64 * ntiles_n
    const int q8  = nwg >> 3, r8 = nwg & 7;
    const int xcd = blockIdx.x & 7, idx = blockIdx.x >> 3;
    const int swz = ((xcd < r8) ? xcd * (q8 + 1) : r8 * (q8 + 1) + (xcd - r8) * q8) + idx;
    const int mtile = swz & 63;          // M_TOK/128 == 64, M-fastest
    const int ntile = swz >> 6;

    const size_t blockM = (size_t)mtile * 128;
    const int    colc   = ntile * 128;   // chunk-local col base

    const unsigned short* Ag = A  + blockM * K_IN;
    const unsigned short* Bg = Bt + (size_t)colc * K_IN;

    // staging: lane l gathers row (l>>3), 16B chunk (l&7); LDS dest linear
    const int r_in = l >> 3;
    const int cch  = l & 7;

#define STAGE_TILES(K0)                                                        \
    do {                                                                       \
        _Pragma("unroll")                                                      \
        for (int qq = 0; qq < 4; qq++) {                                       \
            const int row = w * 32 + qq * 8 + r_in;                            \
            GLOAD16(Ag + (size_t)row * K_IN + (K0) + cch * 8,                  \
                    &As[(w * 32 + qq * 8) * 64]);                              \
        }                                                                      \
        _Pragma("unroll")                                                      \
        for (int qq = 0; qq < 4; qq++) {                                       \
            const int row = w * 32 + qq * 8 + r_in;                            \
            GLOAD16(Bg + (size_t)row * K_IN + (K0) + cch * 8,                  \
                    &Bs[(w * 32 + qq * 8) * 64]);                              \
        }                                                                      \
    } while (0)

    f32x4 acc[4][4];
#pragma unroll
    for (int i = 0; i < 4; i++)
#pragma unroll
        for (int j = 0; j < 4; j++) acc[i][j] = (f32x4){0.f, 0.f, 0.f, 0.f};

    const int lrow = l & 15;
    const int lk   = l >> 4;
    const int NT   = K_IN / 64;

    STAGE_TILES(0);

    for (int kt = 0; kt < NT; ++kt) {
        __syncthreads();            // drains vmcnt: staged tile visible
#pragma unroll
        for (int ks = 0; ks < 2; ++ks) {
            s16x8 a[4], b[4];
            const int kc = ks * 4 + lk;
#pragma unroll
            for (int mi = 0; mi < 4; mi++) {
                const int row = wm * 64 + mi * 16 + lrow;
                a[mi] = *(const s16x8*)&As[row * 64 + kc * 8];
            }
#pragma unroll
            for (int ni = 0; ni < 4; ni++) {
                const int row = wn * 64 + ni * 16 + lrow;
                b[ni] = *(const s16x8*)&Bs[row * 64 + kc * 8];
            }
#pragma unroll
            for (int mi = 0; mi < 4; mi++)
#pragma unroll
                for (int ni = 0; ni < 4; ni++)
                    acc[mi][ni] = __builtin_amdgcn_mfma_f32_16x16x32_bf16(
                        __builtin_bit_cast(bf16x8, a[mi]),
                        __builtin_bit_cast(bf16x8, b[ni]),
                        acc[mi][ni], 0, 0, 0);
        }
        if (kt + 1 < NT) {
            __syncthreads();        // all waves done reading
            STAGE_TILES((kt + 1) * 64);
        }
    }
#undef STAGE_TILES

    // Epilogue: C/D layout col = lane&15, row = (lane>>4)*4 + reg (m89)
#pragma unroll
    for (int ni = 0; ni < 4; ++ni) {
        const int ng = n_base + colc + wn * 64 + ni * 16 + lrow;
        const float bv = bias[ng];
#pragma unroll
        for (int mi = 0; mi < 4; ++mi) {
            f32x4 v = acc[mi][ni];
#pragma unroll
            for (int r = 0; r < 4; r++) {
                const size_t grow = blockM + wm * 64 + mi * 16 + lk * 4 + r;
                C[grow * N_OUT + ng] = v[r] + bv;
            }
        }
    }
}

// ---------------------------------------------------------------------------
// Fallback: fully fused kernel (passed round 4, verbatim).
// ---------------------------------------------------------------------------
__global__ __launch_bounds__(256) void fused_w4a16_kernel(
    const float*        __restrict__ A,
    const unsigned int* __restrict__ qw,
    const unsigned int* __restrict__ qz,
    const float*        __restrict__ sc,
    const float*        __restrict__ bias,
    float*              __restrict__ C)
{
    __shared__ __align__(16) unsigned short As[128 * 64];
    __shared__ __align__(16) unsigned short Bs[128 * 64];

    const int tid = threadIdx.x;
    const int l   = tid & 63;
    const int w   = tid >> 6;
    const int wm  = w >> 1;
    const int wn  = w & 1;
    const size_t blockM = (size_t)blockIdx.x * 128;
    const int    colN   = blockIdx.y * 128;

    const float* Ag = A + blockM * K_IN;

    const int r_in = l >> 3;
    const int cch  = l & 7;
    int    aw_off[4];
    size_t ag_off[4];
#pragma unroll
    for (int qq = 0; qq < 4; qq++) {
        const int row = w * 32 + qq * 8 + r_in;
        aw_off[qq] = row * 64 + ((cch ^ r_in) * 8);
        ag_off[qq] = (size_t)row * K_IN + cch * 8;
    }

    const int kc = tid & 7;
    int ngl[4], j8[4], shn[4], bs_off[4];
#pragma unroll
    for (int p = 0; p < 4; p++) {
        const int nl = p * 32 + (tid >> 3);
        const int ng = colN + nl;
        ngl[p]    = ng;
        j8[p]     = ng >> 3;
        shn[p]    = 4 * (ng & 7);
        bs_off[p] = nl * 64 + ((kc ^ (nl & 7)) * 8);
    }

    f32x4 acc[4][4];
#pragma unroll
    for (int i = 0; i < 4; i++)
#pragma unroll
        for (int j = 0; j < 4; j++) acc[i][j] = (f32x4){0.f, 0.f, 0.f, 0.f};

    const int lrow = l & 15;
    const int lk   = l >> 4;
    const int NT   = K_IN / 64;

    for (int kt = 0; kt < NT; ++kt) {
        const int K0 = kt * 64;
        const int g  = K0 >> 7;

        float4 fa[4][2];
#pragma unroll
        for (int qq = 0; qq < 4; qq++) {
            fa[qq][0] = *(const float4*)(Ag + ag_off[qq] + K0);
            fa[qq][1] = *(const float4*)(Ag + ag_off[qq] + K0 + 4);
        }

        unsigned int q[4][8];
        float sf[4], nzs[4];
#pragma unroll
        for (int p = 0; p < 4; p++) {
            const unsigned int* qp = qw + (size_t)(K0 + kc * 8) * NP8 + j8[p];
#pragma unroll
            for (int i = 0; i < 8; i++) q[p][i] = qp[(size_t)i * NP8];
            const float zf = (float)((qz[(size_t)g * NP8 + j8[p]] >> shn[p]) & 0xFu);
            sf[p]  = sc[(size_t)g * N_OUT + ngl[p]];
            nzs[p] = -zf * sf[p];
        }

        __syncthreads();

#pragma unroll
        for (int qq = 0; qq < 4; qq++) {
            bf16x8 h;
#pragma unroll
            for (int i = 0; i < 4; i++) {
                h[i]     = (__bf16)(((const float*)&fa[qq][0])[i]);
                h[i + 4] = (__bf16)(((const float*)&fa[qq][1])[i]);
            }
            *(int4*)&As[aw_off[qq]] = __builtin_bit_cast(int4, h);
        }
#pragma unroll
        for (int p = 0; p < 4; p++) {
            bf16x8 h;
#pragma unroll
            for (int i = 0; i < 8; i++) {
                const float nib = (float)((q[p][i] >> shn[p]) & 0xFu);
                h[i] = (__bf16)fmaf(nib, sf[p], nzs[p]);
            }
            *(int4*)&Bs[bs_off[p]] = __builtin_bit_cast(int4, h);
        }

        __syncthreads();

#pragma unroll
        for (int ks = 0; ks < 2; ++ks) {
            s16x8 a[4], b[4];
            const int kcc = ks * 4 + lk;
#pragma unroll
            for (int mi = 0; mi < 4; mi++) {
                const int row = wm * 64 + mi * 16 + lrow;
                a[mi] = *(const s16x8*)&As[row * 64 + ((kcc ^ (row & 7)) * 8)];
            }
#pragma unroll
            for (int ni = 0; ni < 4; ni++) {
                const int row = wn * 64 + ni * 16 + lrow;
                b[ni] = *(const s16x8*)&Bs[row * 64 + ((kcc ^ (row & 7)) * 8)];
            }
#pragma unroll
            for (int mi = 0; mi < 4; mi++)
#pragma unroll
                for (int ni = 0; ni < 4; ni++)
                    acc[mi][ni] = __builtin_amdgcn_mfma_f32_16x16x32_bf16(
                        __builtin_bit_cast(bf16x8, a[mi]),
                        __builtin_bit_cast(bf16x8, b[ni]),
                        acc[mi][ni], 0, 0, 0);
        }
    }

#pragma unroll
    for (int ni = 0; ni < 4; ++ni) {
        const int ng = colN + wn * 64 + ni * 16 + lrow;
        const float bv = bias[ng];
#pragma unroll
        for (int mi = 0; mi < 4; ++mi) {
            f32x4 v = acc[mi][ni];
#pragma unroll
            for (int r = 0; r < 4; r++) {
                const size_t grow = blockM + wm * 64 + mi * 16 + lk * 4 + r;
                C[grow * N_OUT + ng] = v[r] + bv;
            }
        }
    }
}

// ---------------------------------------------------------------------------
extern "C" void kernel_launch(void* const* d_in, const int* in_sizes, int n_in,
                              void* d_out, int out_size, void* d_ws, size_t ws_size,
                              hipStream_t stream)
{
    const float*        x    = (const float*)d_in[0];
    const unsigned int* qw   = (const unsigned int*)d_in[1];
    const unsigned int* qz   = (const unsigned int*)d_in[2];
    const float*        sc   = (const float*)d_in[3];
    const float*        bias = (const float*)d_in[4];
    float*              out  = (float*)d_out;

    const size_t XBF    = (size_t)M_TOK * K_IN * 2;   // 64 MiB bf16 x
    const size_t COL128 = (size_t)128 * K_IN * 2;     // 1 MiB per 128 cols of W^T

    if (ws_size >= XBF + COL128) {
        // Tier A (proven firing in r6): convert x once, chunked dequant +
        // m97-structure gemm.
        unsigned short* xb = (unsigned short*)d_ws;
        unsigned short* wt = (unsigned short*)((char*)d_ws + XBF);
        const long n8 = (long)M_TOK * K_IN / 8;
        convert_x_kernel<<<2048, 256, 0, stream>>>(x, xb, n8);

        size_t chunk_cols = ((ws_size - XBF) / COL128) * 128;
        if (chunk_cols > (size_t)N_OUT) chunk_cols = N_OUT;
        for (int n0 = 0; n0 < N_OUT; n0 += (int)chunk_cols) {
            int nc = N_OUT - n0;
            if (nc > (int)chunk_cols) nc = (int)chunk_cols;
            dequant_kernel<<<dim3(K_IN / GS, nc / 128), 256, 0, stream>>>(qw, qz, sc, wt, n0);
            gemm_m97_kernel<<<64 * (nc / 128), 256, 0, stream>>>(xb, wt, bias, out, n0);
        }
    } else {
        // Fallback: fully fused (proven round 4).
        fused_w4a16_kernel<<<dim3(M_TOK / 128, N_OUT / 128), 256, 0, stream>>>(
            x, qw, qz, sc, bias, out);
    }
}

// Round 8
// 989.875 us; speedup vs baseline: 3.5502x; 1.2159x over previous
//
#include <hip/hip_runtime.h>
#include <hip/hip_bf16.h>
#include <cstdint>

// Problem constants (match reference)
#define M_TOK 8192
#define K_IN  4096
#define N_OUT 11008
#define NP8   (N_OUT / 8)   // 1376 packed int32 per row of qweight
#define GS    128           // quant group size

// DTYPE CONTRACT (verified round 4): x/scales/bias/out are float32 on device;
// qweight/qzeros are int32.

typedef __attribute__((ext_vector_type(8))) short  s16x8;
typedef __attribute__((ext_vector_type(8))) __bf16 bf16x8;
typedef __attribute__((ext_vector_type(4))) float  f32x4;

// ---------------------------------------------------------------------------
// x f32 -> bf16, grid-strided, 8 elems/thread/iter.
// ---------------------------------------------------------------------------
__global__ __launch_bounds__(256) void convert_x_kernel(
    const float* __restrict__ in, unsigned short* __restrict__ outp, long n8)
{
    long i = (long)blockIdx.x * blockDim.x + threadIdx.x;
    const long stride = (long)gridDim.x * blockDim.x;
    for (; i < n8; i += stride) {
        const float4 a = ((const float4*)in)[2 * i];
        const float4 b = ((const float4*)in)[2 * i + 1];
        bf16x8 h;
        h[0] = (__bf16)a.x; h[1] = (__bf16)a.y; h[2] = (__bf16)a.z; h[3] = (__bf16)a.w;
        h[4] = (__bf16)b.x; h[5] = (__bf16)b.y; h[6] = (__bf16)b.z; h[7] = (__bf16)b.w;
        ((int4*)outp)[i] = __builtin_bit_cast(int4, h);
    }
}

// ---------------------------------------------------------------------------
// Dequant int4 -> bf16 W^T [nc][K] (chunk-local) into workspace. (r6-proven)
// ---------------------------------------------------------------------------
__global__ __launch_bounds__(256) void dequant_kernel(
    const unsigned int* __restrict__ qw,    // [K][N/8]
    const unsigned int* __restrict__ qz,    // [K/GS][N/8]
    const float*        __restrict__ sc,    // [K/GS][N] f32
    unsigned short*     __restrict__ wt,    // out: [nc][K] bf16 bits
    int n_base)
{
    const int tid = threadIdx.x;
    const int k8  = tid & 15;
    const int n8  = tid >> 4;
    const int g   = blockIdx.x;
    const int k0  = g * GS + k8 * 8;
    const int ncl = blockIdx.y * 128 + n8 * 8;
    const int ng  = n_base + ncl;
    const int j8  = ng >> 3;

    const unsigned int z = qz[(size_t)g * NP8 + j8];

    float s[8];
    *(float4*)&s[0] = *(const float4*)&sc[(size_t)g * N_OUT + ng];
    *(float4*)&s[4] = *(const float4*)&sc[(size_t)g * N_OUT + ng + 4];

    unsigned int q[8];
#pragma unroll
    for (int i = 0; i < 8; i++) q[i] = qw[(size_t)(k0 + i) * NP8 + j8];

#pragma unroll
    for (int t = 0; t < 8; t++) {
        const float sf  = s[t];
        const float nzs = -(float)((z >> (4 * t)) & 0xFu) * sf;
        bf16x8 h;
#pragma unroll
        for (int i = 0; i < 8; i++) {
            const float nib = (float)((q[i] >> (4 * t)) & 0xFu);
            h[i] = (__bf16)fmaf(nib, sf, nzs);
        }
        *(int4*)&wt[(size_t)(ncl + t) * K_IN + k0] = __builtin_bit_cast(int4, h);
    }
}

// ---------------------------------------------------------------------------
// m97-structure bf16 GEMM + T2 swizzle: C = A * Bt^T + bias.
// Staging: global_load_lds width=16 with LINEAR LDS dest; the XOR swizzle is
// applied on the GLOBAL source (lane fetches logical chunk cch ^ r_in) and on
// the ds_read (physical chunk = kc ^ (row&7)) — rule-21 both-sides pattern.
// Kills the r7-measured 2.7e8 bank-conflict cycles (16 lanes hitting one
// 4-bank group at 128B row stride).
// ---------------------------------------------------------------------------
#define GLOAD16(gp, lp)                                                        \
    __builtin_amdgcn_global_load_lds(                                          \
        (const __attribute__((address_space(1))) void*)(gp),                   \
        (__attribute__((address_space(3))) void*)(lp), 16, 0, 0)

__global__ __launch_bounds__(256) void gemm_m97_kernel(
    const unsigned short* __restrict__ A,     // xb [M][K] bf16
    const unsigned short* __restrict__ Bt,    // wt chunk [nc][K] bf16
    const float*          __restrict__ bias,  // [N] f32
    float*                __restrict__ C,     // [M][N] f32
    int n_base)
{
    __shared__ __align__(16) unsigned short As[128 * 64];
    __shared__ __align__(16) unsigned short Bs[128 * 64];

    const int tid = threadIdx.x;
    const int l   = tid & 63;
    const int w   = tid >> 6;       // wave 0..3
    const int wm  = w >> 1;
    const int wn  = w & 1;

    // --- bijective XCD swizzle (m204): consecutive swz ids share an N-panel
    const int nwg = gridDim.x;           // 64 * ntiles_n
    const int q8  = nwg >> 3, r8 = nwg & 7;
    const int xcd = blockIdx.x & 7, idx = blockIdx.x >> 3;
    const int swz = ((xcd < r8) ? xcd * (q8 + 1) : r8 * (q8 + 1) + (xcd - r8) * q8) + idx;
    const int mtile = swz & 63;          // M_TOK/128 == 64, M-fastest
    const int ntile = swz >> 6;

    const size_t blockM = (size_t)mtile * 128;
    const int    colc   = ntile * 128;   // chunk-local col base

    const unsigned short* Ag = A  + blockM * K_IN;
    const unsigned short* Bg = Bt + (size_t)colc * K_IN;

    // staging: lane l covers row (l>>3), PHYSICAL chunk (l&7); LDS dest linear
    // => fetch LOGICAL chunk (cch ^ r_in) from global (inverse swizzle).
    const int r_in = l >> 3;
    const int cch  = l & 7;
    const int kcs  = cch ^ r_in;

#define STAGE_TILES(K0)                                                        \
    do {                                                                       \
        _Pragma("unroll")                                                      \
        for (int qq = 0; qq < 4; qq++) {                                       \
            const int row = w * 32 + qq * 8 + r_in;                            \
            GLOAD16(Ag + (size_t)row * K_IN + (K0) + kcs * 8,                  \
                    &As[(w * 32 + qq * 8) * 64]);                              \
        }                                                                      \
        _Pragma("unroll")                                                      \
        for (int qq = 0; qq < 4; qq++) {                                       \
            const int row = w * 32 + qq * 8 + r_in;                            \
            GLOAD16(Bg + (size_t)row * K_IN + (K0) + kcs * 8,                  \
                    &Bs[(w * 32 + qq * 8) * 64]);                              \
        }                                                                      \
    } while (0)

    f32x4 acc[4][4];
#pragma unroll
    for (int i = 0; i < 4; i++)
#pragma unroll
        for (int j = 0; j < 4; j++) acc[i][j] = (f32x4){0.f, 0.f, 0.f, 0.f};

    const int lrow = l & 15;
    const int lk   = l >> 4;
    const int NT   = K_IN / 64;

    STAGE_TILES(0);

    for (int kt = 0; kt < NT; ++kt) {
        __syncthreads();            // drains vmcnt: staged tile visible
#pragma unroll
        for (int ks = 0; ks < 2; ++ks) {
            s16x8 a[4], b[4];
            const int kc = ks * 4 + lk;   // logical chunk
#pragma unroll
            for (int mi = 0; mi < 4; mi++) {
                const int row = wm * 64 + mi * 16 + lrow;
                a[mi] = *(const s16x8*)&As[row * 64 + ((kc ^ (row & 7)) * 8)];
            }
#pragma unroll
            for (int ni = 0; ni < 4; ni++) {
                const int row = wn * 64 + ni * 16 + lrow;
                b[ni] = *(const s16x8*)&Bs[row * 64 + ((kc ^ (row & 7)) * 8)];
            }
#pragma unroll
            for (int mi = 0; mi < 4; mi++)
#pragma unroll
                for (int ni = 0; ni < 4; ni++)
                    acc[mi][ni] = __builtin_amdgcn_mfma_f32_16x16x32_bf16(
                        __builtin_bit_cast(bf16x8, a[mi]),
                        __builtin_bit_cast(bf16x8, b[ni]),
                        acc[mi][ni], 0, 0, 0);
        }
        if (kt + 1 < NT) {
            __syncthreads();        // all waves done reading
            STAGE_TILES((kt + 1) * 64);
        }
    }
#undef STAGE_TILES

    // Epilogue: C/D layout col = lane&15, row = (lane>>4)*4 + reg (m89)
#pragma unroll
    for (int ni = 0; ni < 4; ++ni) {
        const int ng = n_base + colc + wn * 64 + ni * 16 + lrow;
        const float bv = bias[ng];
#pragma unroll
        for (int mi = 0; mi < 4; ++mi) {
            f32x4 v = acc[mi][ni];
#pragma unroll
            for (int r = 0; r < 4; r++) {
                const size_t grow = blockM + wm * 64 + mi * 16 + lk * 4 + r;
                C[grow * N_OUT + ng] = v[r] + bv;
            }
        }
    }
}

// ---------------------------------------------------------------------------
// Fallback: fully fused kernel (passed round 4, verbatim).
// ---------------------------------------------------------------------------
__global__ __launch_bounds__(256) void fused_w4a16_kernel(
    const float*        __restrict__ A,
    const unsigned int* __restrict__ qw,
    const unsigned int* __restrict__ qz,
    const float*        __restrict__ sc,
    const float*        __restrict__ bias,
    float*              __restrict__ C)
{
    __shared__ __align__(16) unsigned short As[128 * 64];
    __shared__ __align__(16) unsigned short Bs[128 * 64];

    const int tid = threadIdx.x;
    const int l   = tid & 63;
    const int w   = tid >> 6;
    const int wm  = w >> 1;
    const int wn  = w & 1;
    const size_t blockM = (size_t)blockIdx.x * 128;
    const int    colN   = blockIdx.y * 128;

    const float* Ag = A + blockM * K_IN;

    const int r_in = l >> 3;
    const int cch  = l & 7;
    int    aw_off[4];
    size_t ag_off[4];
#pragma unroll
    for (int qq = 0; qq < 4; qq++) {
        const int row = w * 32 + qq * 8 + r_in;
        aw_off[qq] = row * 64 + ((cch ^ r_in) * 8);
        ag_off[qq] = (size_t)row * K_IN + cch * 8;
    }

    const int kc = tid & 7;
    int ngl[4], j8[4], shn[4], bs_off[4];
#pragma unroll
    for (int p = 0; p < 4; p++) {
        const int nl = p * 32 + (tid >> 3);
        const int ng = colN + nl;
        ngl[p]    = ng;
        j8[p]     = ng >> 3;
        shn[p]    = 4 * (ng & 7);
        bs_off[p] = nl * 64 + ((kc ^ (nl & 7)) * 8);
    }

    f32x4 acc[4][4];
#pragma unroll
    for (int i = 0; i < 4; i++)
#pragma unroll
        for (int j = 0; j < 4; j++) acc[i][j] = (f32x4){0.f, 0.f, 0.f, 0.f};

    const int lrow = l & 15;
    const int lk   = l >> 4;
    const int NT   = K_IN / 64;

    for (int kt = 0; kt < NT; ++kt) {
        const int K0 = kt * 64;
        const int g  = K0 >> 7;

        float4 fa[4][2];
#pragma unroll
        for (int qq = 0; qq < 4; qq++) {
            fa[qq][0] = *(const float4*)(Ag + ag_off[qq] + K0);
            fa[qq][1] = *(const float4*)(Ag + ag_off[qq] + K0 + 4);
        }

        unsigned int q[4][8];
        float sf[4], nzs[4];
#pragma unroll
        for (int p = 0; p < 4; p++) {
            const unsigned int* qp = qw + (size_t)(K0 + kc * 8) * NP8 + j8[p];
#pragma unroll
            for (int i = 0; i < 8; i++) q[p][i] = qp[(size_t)i * NP8];
            const float zf = (float)((qz[(size_t)g * NP8 + j8[p]] >> shn[p]) & 0xFu);
            sf[p]  = sc[(size_t)g * N_OUT + ngl[p]];
            nzs[p] = -zf * sf[p];
        }

        __syncthreads();

#pragma unroll
        for (int qq = 0; qq < 4; qq++) {
            bf16x8 h;
#pragma unroll
            for (int i = 0; i < 4; i++) {
                h[i]     = (__bf16)(((const float*)&fa[qq][0])[i]);
                h[i + 4] = (__bf16)(((const float*)&fa[qq][1])[i]);
            }
            *(int4*)&As[aw_off[qq]] = __builtin_bit_cast(int4, h);
        }
#pragma unroll
        for (int p = 0; p < 4; p++) {
            bf16x8 h;
#pragma unroll
            for (int i = 0; i < 8; i++) {
                const float nib = (float)((q[p][i] >> shn[p]) & 0xFu);
                h[i] = (__bf16)fmaf(nib, sf[p], nzs[p]);
            }
            *(int4*)&Bs[bs_off[p]] = __builtin_bit_cast(int4, h);
        }

        __syncthreads();

#pragma unroll
        for (int ks = 0; ks < 2; ++ks) {
            s16x8 a[4], b[4];
            const int kcc = ks * 4 + lk;
#pragma unroll
            for (int mi = 0; mi < 4; mi++) {
                const int row = wm * 64 + mi * 16 + lrow;
                a[mi] = *(const s16x8*)&As[row * 64 + ((kcc ^ (row & 7)) * 8)];
            }
#pragma unroll
            for (int ni = 0; ni < 4; ni++) {
                const int row = wn * 64 + ni * 16 + lrow;
                b[ni] = *(const s16x8*)&Bs[row * 64 + ((kcc ^ (row & 7)) * 8)];
            }
#pragma unroll
            for (int mi = 0; mi < 4; mi++)
#pragma unroll
                for (int ni = 0; ni < 4; ni++)
                    acc[mi][ni] = __builtin_amdgcn_mfma_f32_16x16x32_bf16(
                        __builtin_bit_cast(bf16x8, a[mi]),
                        __builtin_bit_cast(bf16x8, b[ni]),
                        acc[mi][ni], 0, 0, 0);
        }
    }

#pragma unroll
    for (int ni = 0; ni < 4; ++ni) {
        const int ng = colN + wn * 64 + ni * 16 + lrow;
        const float bv = bias[ng];
#pragma unroll
        for (int mi = 0; mi < 4; ++mi) {
            f32x4 v = acc[mi][ni];
#pragma unroll
            for (int r = 0; r < 4; r++) {
                const size_t grow = blockM + wm * 64 + mi * 16 + lk * 4 + r;
                C[grow * N_OUT + ng] = v[r] + bv;
            }
        }
    }
}

// ---------------------------------------------------------------------------
extern "C" void kernel_launch(void* const* d_in, const int* in_sizes, int n_in,
                              void* d_out, int out_size, void* d_ws, size_t ws_size,
                              hipStream_t stream)
{
    const float*        x    = (const float*)d_in[0];
    const unsigned int* qw   = (const unsigned int*)d_in[1];
    const unsigned int* qz   = (const unsigned int*)d_in[2];
    const float*        sc   = (const float*)d_in[3];
    const float*        bias = (const float*)d_in[4];
    float*              out  = (float*)d_out;

    const size_t XBF    = (size_t)M_TOK * K_IN * 2;   // 64 MiB bf16 x
    const size_t COL128 = (size_t)128 * K_IN * 2;     // 1 MiB per 128 cols of W^T

    if (ws_size >= XBF + COL128) {
        // Tier A (proven firing in r6/r7): convert x once, chunked dequant +
        // swizzled m97 gemm.
        unsigned short* xb = (unsigned short*)d_ws;
        unsigned short* wt = (unsigned short*)((char*)d_ws + XBF);
        const long n8 = (long)M_TOK * K_IN / 8;
        convert_x_kernel<<<2048, 256, 0, stream>>>(x, xb, n8);

        size_t chunk_cols = ((ws_size - XBF) / COL128) * 128;
        if (chunk_cols > (size_t)N_OUT) chunk_cols = N_OUT;
        for (int n0 = 0; n0 < N_OUT; n0 += (int)chunk_cols) {
            int nc = N_OUT - n0;
            if (nc > (int)chunk_cols) nc = (int)chunk_cols;
            dequant_kernel<<<dim3(K_IN / GS, nc / 128), 256, 0, stream>>>(qw, qz, sc, wt, n0);
            gemm_m97_kernel<<<64 * (nc / 128), 256, 0, stream>>>(xb, wt, bias, out, n0);
        }
    } else {
        // Fallback: fully fused (proven round 4).
        fused_w4a16_kernel<<<dim3(M_TOK / 128, N_OUT / 128), 256, 0, stream>>>(
            x, qw, qz, sc, bias, out);
    }
}

// Round 9
// 895.343 us; speedup vs baseline: 3.9250x; 1.1056x over previous
//
#include <hip/hip_runtime.h>
#include <hip/hip_bf16.h>
#include <cstdint>

// Problem constants (match reference)
#define M_TOK 8192
#define K_IN  4096
#define N_OUT 11008
#define NP8   (N_OUT / 8)   // 1376 packed int32 per row of qweight
#define GS    128           // quant group size

// DTYPE CONTRACT (verified round 4): x/scales/bias/out are float32 on device;
// qweight/qzeros are int32.

typedef __attribute__((ext_vector_type(8))) short  s16x8;
typedef __attribute__((ext_vector_type(8))) __bf16 bf16x8;
typedef __attribute__((ext_vector_type(4))) float  f32x4;

// ---------------------------------------------------------------------------
// x f32 -> bf16, grid-strided, 8 elems/thread/iter. (r6-proven)
// ---------------------------------------------------------------------------
__global__ __launch_bounds__(256) void convert_x_kernel(
    const float* __restrict__ in, unsigned short* __restrict__ outp, long n8)
{
    long i = (long)blockIdx.x * blockDim.x + threadIdx.x;
    const long stride = (long)gridDim.x * blockDim.x;
    for (; i < n8; i += stride) {
        const float4 a = ((const float4*)in)[2 * i];
        const float4 b = ((const float4*)in)[2 * i + 1];
        bf16x8 h;
        h[0] = (__bf16)a.x; h[1] = (__bf16)a.y; h[2] = (__bf16)a.z; h[3] = (__bf16)a.w;
        h[4] = (__bf16)b.x; h[5] = (__bf16)b.y; h[6] = (__bf16)b.z; h[7] = (__bf16)b.w;
        ((int4*)outp)[i] = __builtin_bit_cast(int4, h);
    }
}

// ---------------------------------------------------------------------------
// Dequant int4 -> bf16 W^T [nc][K] (chunk-local) into workspace. (r6-proven)
// ---------------------------------------------------------------------------
__global__ __launch_bounds__(256) void dequant_kernel(
    const unsigned int* __restrict__ qw,    // [K][N/8]
    const unsigned int* __restrict__ qz,    // [K/GS][N/8]
    const float*        __restrict__ sc,    // [K/GS][N] f32
    unsigned short*     __restrict__ wt,    // out: [nc][K] bf16 bits
    int n_base)
{
    const int tid = threadIdx.x;
    const int k8  = tid & 15;
    const int n8  = tid >> 4;
    const int g   = blockIdx.x;
    const int k0  = g * GS + k8 * 8;
    const int ncl = blockIdx.y * 128 + n8 * 8;
    const int ng  = n_base + ncl;
    const int j8  = ng >> 3;

    const unsigned int z = qz[(size_t)g * NP8 + j8];

    float s[8];
    *(float4*)&s[0] = *(const float4*)&sc[(size_t)g * N_OUT + ng];
    *(float4*)&s[4] = *(const float4*)&sc[(size_t)g * N_OUT + ng + 4];

    unsigned int q[8];
#pragma unroll
    for (int i = 0; i < 8; i++) q[i] = qw[(size_t)(k0 + i) * NP8 + j8];

#pragma unroll
    for (int t = 0; t < 8; t++) {
        const float sf  = s[t];
        const float nzs = -(float)((z >> (4 * t)) & 0xFu) * sf;
        bf16x8 h;
#pragma unroll
        for (int i = 0; i < 8; i++) {
            const float nib = (float)((q[i] >> (4 * t)) & 0xFu);
            h[i] = (__bf16)fmaf(nib, sf, nzs);
        }
        *(int4*)&wt[(size_t)(ncl + t) * K_IN + k0] = __builtin_bit_cast(int4, h);
    }
}

// ---------------------------------------------------------------------------
// 256x256 deep-pipelined bf16 GEMM (T1+T2+T3+T4): C = A * Bt^T + bias.
// BK=32, 4-deep LDS ring (4 x 32KB = 128KB), 8 waves (2M x 4N), 512 thr.
// Per iter: vmcnt(8) [counted, never 0 until tail] -> s_barrier ->
// STAGE(t+3) into ring slot (t+3)&3 [= slot read in iter t-1; safe by the
// collective barrier] -> 12 swizzled ds_read_b128 -> 32 MFMA.
// T2 swizzle for 64B rows: physical 16B chunk = kc ^ ((row>>1)&3), applied
// as inverse on the global gather (linear LDS dest) and on ds_read.
// ---------------------------------------------------------------------------
#define GLOAD16(gp, lp)                                                        \
    __builtin_amdgcn_global_load_lds(                                          \
        (const __attribute__((address_space(1))) void*)(gp),                   \
        (__attribute__((address_space(3))) void*)(lp), 16, 0, 0)

__global__ __launch_bounds__(512, 2) void gemm_256_kernel(
    const unsigned short* __restrict__ A,     // xb [M][K] bf16
    const unsigned short* __restrict__ Bt,    // wt chunk [nc][K] bf16
    const float*          __restrict__ bias,  // [N] f32
    float*                __restrict__ C,     // [M][N] f32
    int n_base)
{
    __shared__ __align__(16) unsigned short lds[4][2][256 * 32];  // [buf][A/B]

    const int tid = threadIdx.x;
    const int l   = tid & 63;
    const int w   = tid >> 6;       // wave 0..7
    const int wm  = w >> 2;         // 0..1  (M half: 128 rows)
    const int wn  = w & 3;          // 0..3  (N quarter: 64 cols)

    // --- bijective XCD swizzle (m204), M-fastest within swz order
    const int nwg = gridDim.x;      // 32 * ntiles_n
    const int q8  = nwg >> 3, r8 = nwg & 7;
    const int xcd = blockIdx.x & 7, idx = blockIdx.x >> 3;
    const int swz = ((xcd < r8) ? xcd * (q8 + 1) : r8 * (q8 + 1) + (xcd - r8) * q8) + idx;
    const int mtile = swz & 31;     // M_TOK/256 == 32
    const int ntile = swz >> 5;

    const size_t blockM = (size_t)mtile * 256;
    const int    colc   = ntile * 256;   // chunk-local col base

    const unsigned short* Ag = A  + blockM * K_IN;
    const unsigned short* Bg = Bt + (size_t)colc * K_IN;

    // --- staging roles: 4 lanes/row (16B each), 16 rows per wave-load
    const int r_in = l >> 2;                 // 0..15
    const int cch  = l & 3;                  // physical chunk
    const int kcs  = cch ^ ((r_in >> 1) & 3);// logical chunk to gather (inverse swz)

    int g_off[2];   // element offset within panel for load q (A and B identical)
#pragma unroll
    for (int q = 0; q < 2; q++)
        g_off[q] = (w * 32 + q * 16 + r_in) * K_IN + kcs * 8;

#define STAGE(tt)                                                              \
    do {                                                                       \
        const int    _bb = (tt) & 3;                                           \
        const size_t _ko = (size_t)(tt) * 32;                                  \
        _Pragma("unroll")                                                      \
        for (int q = 0; q < 2; q++)                                            \
            GLOAD16(Ag + g_off[q] + _ko, &lds[_bb][0][(w * 32 + q * 16) * 32]);\
        _Pragma("unroll")                                                      \
        for (int q = 0; q < 2; q++)                                            \
            GLOAD16(Bg + g_off[q] + _ko, &lds[_bb][1][(w * 32 + q * 16) * 32]);\
    } while (0)

    // --- compute roles
    const int lrow = l & 15;
    const int kc   = l >> 4;                 // 0..3 (16B k-chunk)
    const int kswz = (lrow >> 1) & 3;
    const int pch  = (kc ^ kswz) * 8;        // physical chunk byte/2 offset

    int aoff[8], boff[4];
#pragma unroll
    for (int mi = 0; mi < 8; mi++)
        aoff[mi] = (wm * 128 + mi * 16 + lrow) * 32 + pch;
#pragma unroll
    for (int ni = 0; ni < 4; ni++)
        boff[ni] = (wn * 64 + ni * 16 + lrow) * 32 + pch;

    f32x4 acc[8][4];
#pragma unroll
    for (int i = 0; i < 8; i++)
#pragma unroll
        for (int j = 0; j < 4; j++) acc[i][j] = (f32x4){0.f, 0.f, 0.f, 0.f};

    const int NT = K_IN / 32;    // 128

    STAGE(0); STAGE(1); STAGE(2);   // 12 loads in flight

    for (int t = 0; t < NT; ++t) {
        // counted vmcnt: wait only for tile t's 4 loads (t+1,t+2 stay in flight)
        if (t < NT - 2)       asm volatile("s_waitcnt vmcnt(8)" ::: "memory");
        else if (t == NT - 2) asm volatile("s_waitcnt vmcnt(4)" ::: "memory");
        else                  asm volatile("s_waitcnt vmcnt(0)" ::: "memory");
        __builtin_amdgcn_s_barrier();        // collective: tile t fully in LDS,
        __builtin_amdgcn_sched_barrier(0);   // and slot (t+3)&3 free to overwrite

        if (t + 3 < NT) STAGE(t + 3);        // issue overlaps with ds_read+MFMA

        const unsigned short* Ab = &lds[t & 3][0][0];
        const unsigned short* Bb = &lds[t & 3][1][0];
        s16x8 a[8], b[4];
#pragma unroll
        for (int mi = 0; mi < 8; mi++) a[mi] = *(const s16x8*)&Ab[aoff[mi]];
#pragma unroll
        for (int ni = 0; ni < 4; ni++) b[ni] = *(const s16x8*)&Bb[boff[ni]];
#pragma unroll
        for (int mi = 0; mi < 8; mi++)
#pragma unroll
            for (int ni = 0; ni < 4; ni++)
                acc[mi][ni] = __builtin_amdgcn_mfma_f32_16x16x32_bf16(
                    __builtin_bit_cast(bf16x8, a[mi]),
                    __builtin_bit_cast(bf16x8, b[ni]),
                    acc[mi][ni], 0, 0, 0);
    }
#undef STAGE

    // Epilogue: C/D layout col = lane&15, row = (lane>>4)*4 + reg (m89)
#pragma unroll
    for (int ni = 0; ni < 4; ++ni) {
        const int ng = n_base + colc + wn * 64 + ni * 16 + lrow;
        const float bv = bias[ng];
#pragma unroll
        for (int mi = 0; mi < 8; ++mi) {
            f32x4 v = acc[mi][ni];
#pragma unroll
            for (int r = 0; r < 4; r++) {
                const size_t grow = blockM + wm * 128 + mi * 16 + kc * 4 + r;
                C[grow * N_OUT + ng] = v[r] + bv;
            }
        }
    }
}

// ---------------------------------------------------------------------------
// Fallback: fully fused kernel (passed round 4, verbatim).
// ---------------------------------------------------------------------------
__global__ __launch_bounds__(256) void fused_w4a16_kernel(
    const float*        __restrict__ A,
    const unsigned int* __restrict__ qw,
    const unsigned int* __restrict__ qz,
    const float*        __restrict__ sc,
    const float*        __restrict__ bias,
    float*              __restrict__ C)
{
    __shared__ __align__(16) unsigned short As[128 * 64];
    __shared__ __align__(16) unsigned short Bs[128 * 64];

    const int tid = threadIdx.x;
    const int l   = tid & 63;
    const int w   = tid >> 6;
    const int wm  = w >> 1;
    const int wn  = w & 1;
    const size_t blockM = (size_t)blockIdx.x * 128;
    const int    colN   = blockIdx.y * 128;

    const float* Ag = A + blockM * K_IN;

    const int r_in = l >> 3;
    const int cch  = l & 7;
    int    aw_off[4];
    size_t ag_off[4];
#pragma unroll
    for (int qq = 0; qq < 4; qq++) {
        const int row = w * 32 + qq * 8 + r_in;
        aw_off[qq] = row * 64 + ((cch ^ r_in) * 8);
        ag_off[qq] = (size_t)row * K_IN + cch * 8;
    }

    const int kc = tid & 7;
    int ngl[4], j8[4], shn[4], bs_off[4];
#pragma unroll
    for (int p = 0; p < 4; p++) {
        const int nl = p * 32 + (tid >> 3);
        const int ng = colN + nl;
        ngl[p]    = ng;
        j8[p]     = ng >> 3;
        shn[p]    = 4 * (ng & 7);
        bs_off[p] = nl * 64 + ((kc ^ (nl & 7)) * 8);
    }

    f32x4 acc[4][4];
#pragma unroll
    for (int i = 0; i < 4; i++)
#pragma unroll
        for (int j = 0; j < 4; j++) acc[i][j] = (f32x4){0.f, 0.f, 0.f, 0.f};

    const int lrow = l & 15;
    const int lk   = l >> 4;
    const int NT   = K_IN / 64;

    for (int kt = 0; kt < NT; ++kt) {
        const int K0 = kt * 64;
        const int g  = K0 >> 7;

        float4 fa[4][2];
#pragma unroll
        for (int qq = 0; qq < 4; qq++) {
            fa[qq][0] = *(const float4*)(Ag + ag_off[qq] + K0);
            fa[qq][1] = *(const float4*)(Ag + ag_off[qq] + K0 + 4);
        }

        unsigned int q[4][8];
        float sf[4], nzs[4];
#pragma unroll
        for (int p = 0; p < 4; p++) {
            const unsigned int* qp = qw + (size_t)(K0 + kc * 8) * NP8 + j8[p];
#pragma unroll
            for (int i = 0; i < 8; i++) q[p][i] = qp[(size_t)i * NP8];
            const float zf = (float)((qz[(size_t)g * NP8 + j8[p]] >> shn[p]) & 0xFu);
            sf[p]  = sc[(size_t)g * N_OUT + ngl[p]];
            nzs[p] = -zf * sf[p];
        }

        __syncthreads();

#pragma unroll
        for (int qq = 0; qq < 4; qq++) {
            bf16x8 h;
#pragma unroll
            for (int i = 0; i < 4; i++) {
                h[i]     = (__bf16)(((const float*)&fa[qq][0])[i]);
                h[i + 4] = (__bf16)(((const float*)&fa[qq][1])[i]);
            }
            *(int4*)&As[aw_off[qq]] = __builtin_bit_cast(int4, h);
        }
#pragma unroll
        for (int p = 0; p < 4; p++) {
            bf16x8 h;
#pragma unroll
            for (int i = 0; i < 8; i++) {
                const float nib = (float)((q[p][i] >> shn[p]) & 0xFu);
                h[i] = (__bf16)fmaf(nib, sf[p], nzs[p]);
            }
            *(int4*)&Bs[bs_off[p]] = __builtin_bit_cast(int4, h);
        }

        __syncthreads();

#pragma unroll
        for (int ks = 0; ks < 2; ++ks) {
            s16x8 a[4], b[4];
            const int kcc = ks * 4 + lk;
#pragma unroll
            for (int mi = 0; mi < 4; mi++) {
                const int row = wm * 64 + mi * 16 + lrow;
                a[mi] = *(const s16x8*)&As[row * 64 + ((kcc ^ (row & 7)) * 8)];
            }
#pragma unroll
            for (int ni = 0; ni < 4; ni++) {
                const int row = wn * 64 + ni * 16 + lrow;
                b[ni] = *(const s16x8*)&Bs[row * 64 + ((kcc ^ (row & 7)) * 8)];
            }
#pragma unroll
            for (int mi = 0; mi < 4; mi++)
#pragma unroll
                for (int ni = 0; ni < 4; ni++)
                    acc[mi][ni] = __builtin_amdgcn_mfma_f32_16x16x32_bf16(
                        __builtin_bit_cast(bf16x8, a[mi]),
                        __builtin_bit_cast(bf16x8, b[ni]),
                        acc[mi][ni], 0, 0, 0);
        }
    }

#pragma unroll
    for (int ni = 0; ni < 4; ++ni) {
        const int ng = colN + wn * 64 + ni * 16 + lrow;
        const float bv = bias[ng];
#pragma unroll
        for (int mi = 0; mi < 4; ++mi) {
            f32x4 v = acc[mi][ni];
#pragma unroll
            for (int r = 0; r < 4; r++) {
                const size_t grow = blockM + wm * 64 + mi * 16 + lk * 4 + r;
                C[grow * N_OUT + ng] = v[r] + bv;
            }
        }
    }
}

// ---------------------------------------------------------------------------
extern "C" void kernel_launch(void* const* d_in, const int* in_sizes, int n_in,
                              void* d_out, int out_size, void* d_ws, size_t ws_size,
                              hipStream_t stream)
{
    const float*        x    = (const float*)d_in[0];
    const unsigned int* qw   = (const unsigned int*)d_in[1];
    const unsigned int* qz   = (const unsigned int*)d_in[2];
    const float*        sc   = (const float*)d_in[3];
    const float*        bias = (const float*)d_in[4];
    float*              out  = (float*)d_out;

    const size_t XBF    = (size_t)M_TOK * K_IN * 2;   // 64 MiB bf16 x
    const size_t COL256 = (size_t)256 * K_IN * 2;     // 2 MiB per 256 cols of W^T

    if (ws_size >= XBF + COL256) {
        // Tier A (proven firing r6-r8): convert x once, chunked dequant +
        // 256x256 deep-pipelined gemm.
        unsigned short* xb = (unsigned short*)d_ws;
        unsigned short* wt = (unsigned short*)((char*)d_ws + XBF);
        const long n8 = (long)M_TOK * K_IN / 8;
        convert_x_kernel<<<2048, 256, 0, stream>>>(x, xb, n8);

        size_t chunk_cols = ((ws_size - XBF) / COL256) * 256;
        if (chunk_cols > (size_t)N_OUT) chunk_cols = N_OUT;
        for (int n0 = 0; n0 < N_OUT; n0 += (int)chunk_cols) {
            int nc = N_OUT - n0;
            if (nc > (int)chunk_cols) nc = (int)chunk_cols;
            dequant_kernel<<<dim3(K_IN / GS, nc / 128), 256, 0, stream>>>(qw, qz, sc, wt, n0);
            gemm_256_kernel<<<32 * (nc / 256), 512, 0, stream>>>(xb, wt, bias, out, n0);
        }
    } else {
        // Fallback: fully fused (proven round 4).
        fused_w4a16_kernel<<<dim3(M_TOK / 128, N_OUT / 128), 256, 0, stream>>>(
            x, qw, qz, sc, bias, out);
    }
}

// Round 11
// 871.803 us; speedup vs baseline: 4.0310x; 1.0270x over previous
//
#include <hip/hip_runtime.h>
#include <hip/hip_bf16.h>
#include <cstdint>

// Problem constants (match reference)
#define M_TOK 8192
#define K_IN  4096
#define N_OUT 11008
#define NP8   (N_OUT / 8)   // 1376 packed int32 per row of qweight
#define GS    128           // quant group size

// DTYPE CONTRACT (verified round 4): x/scales/bias/out are float32 on device;
// qweight/qzeros are int32.

typedef __attribute__((ext_vector_type(8))) short  s16x8;
typedef __attribute__((ext_vector_type(8))) __bf16 bf16x8;
typedef __attribute__((ext_vector_type(4))) float  f32x4;

// ---------------------------------------------------------------------------
// x f32 -> bf16, grid-strided, 8 elems/thread/iter. (r6-proven)
// ---------------------------------------------------------------------------
__global__ __launch_bounds__(256) void convert_x_kernel(
    const float* __restrict__ in, unsigned short* __restrict__ outp, long n8)
{
    long i = (long)blockIdx.x * blockDim.x + threadIdx.x;
    const long stride = (long)gridDim.x * blockDim.x;
    for (; i < n8; i += stride) {
        const float4 a = ((const float4*)in)[2 * i];
        const float4 b = ((const float4*)in)[2 * i + 1];
        bf16x8 h;
        h[0] = (__bf16)a.x; h[1] = (__bf16)a.y; h[2] = (__bf16)a.z; h[3] = (__bf16)a.w;
        h[4] = (__bf16)b.x; h[5] = (__bf16)b.y; h[6] = (__bf16)b.z; h[7] = (__bf16)b.w;
        ((int4*)outp)[i] = __builtin_bit_cast(int4, h);
    }
}

// ---------------------------------------------------------------------------
// Dequant int4 -> bf16 W^T [nc][K] (chunk-local) into workspace. (r6-proven)
// ---------------------------------------------------------------------------
__global__ __launch_bounds__(256) void dequant_kernel(
    const unsigned int* __restrict__ qw,    // [K][N/8]
    const unsigned int* __restrict__ qz,    // [K/GS][N/8]
    const float*        __restrict__ sc,    // [K/GS][N] f32
    unsigned short*     __restrict__ wt,    // out: [nc][K] bf16 bits
    int n_base)
{
    const int tid = threadIdx.x;
    const int k8  = tid & 15;
    const int n8  = tid >> 4;
    const int g   = blockIdx.x;
    const int k0  = g * GS + k8 * 8;
    const int ncl = blockIdx.y * 128 + n8 * 8;
    const int ng  = n_base + ncl;
    const int j8  = ng >> 3;

    const unsigned int z = qz[(size_t)g * NP8 + j8];

    float s[8];
    *(float4*)&s[0] = *(const float4*)&sc[(size_t)g * N_OUT + ng];
    *(float4*)&s[4] = *(const float4*)&sc[(size_t)g * N_OUT + ng + 4];

    unsigned int q[8];
#pragma unroll
    for (int i = 0; i < 8; i++) q[i] = qw[(size_t)(k0 + i) * NP8 + j8];

#pragma unroll
    for (int t = 0; t < 8; t++) {
        const float sf  = s[t];
        const float nzs = -(float)((z >> (4 * t)) & 0xFu) * sf;
        bf16x8 h;
#pragma unroll
        for (int i = 0; i < 8; i++) {
            const float nib = (float)((q[i] >> (4 * t)) & 0xFu);
            h[i] = (__bf16)fmaf(nib, sf, nzs);
        }
        *(int4*)&wt[(size_t)(ncl + t) * K_IN + k0] = __builtin_bit_cast(int4, h);
    }
}

// ---------------------------------------------------------------------------
// 256x256 deep-pipelined bf16 GEMM (T1+T2+T3+T4+T5): C = A * Bt^T + bias.
// BK=32, 4-deep LDS ring, 8 waves (2M x 4N), 512 thr.
// r10/r11: register double-buffer of fragments — step t MFMAs tile t's
// frags (read last step) while issuing ds_reads for tile t+1. Counted
// vmcnt(4) guarantees tile t+1 resident before its reads. setprio(1)
// around the MFMA cluster (T5; phase-split structure => m224 regime).
// ---------------------------------------------------------------------------
#define GLOAD16(gp, lp)                                                        \
    __builtin_amdgcn_global_load_lds(                                          \
        (const __attribute__((address_space(1))) void*)(gp),                   \
        (__attribute__((address_space(3))) void*)(lp), 16, 0, 0)

__global__ __launch_bounds__(512, 2) void gemm_256_kernel(
    const unsigned short* __restrict__ A,     // xb [M][K] bf16
    const unsigned short* __restrict__ Bt,    // wt chunk [nc][K] bf16
    const float*          __restrict__ bias,  // [N] f32
    float*                __restrict__ C,     // [M][N] f32
    int n_base)
{
    __shared__ __align__(16) unsigned short lds[4][2][256 * 32];  // [buf][A/B]

    const int tid = threadIdx.x;
    const int l   = tid & 63;
    const int w   = tid >> 6;       // wave 0..7
    const int wm  = w >> 2;         // 0..1  (M half: 128 rows)
    const int wn  = w & 3;          // 0..3  (N quarter: 64 cols)

    // --- bijective XCD swizzle (m204), M-fastest within swz order
    const int nwg = gridDim.x;      // 32 * ntiles_n
    const int q8  = nwg >> 3, r8 = nwg & 7;
    const int xcd = blockIdx.x & 7, idx = blockIdx.x >> 3;
    const int swz = ((xcd < r8) ? xcd * (q8 + 1) : r8 * (q8 + 1) + (xcd - r8) * q8) + idx;
    const int mtile = swz & 31;     // M_TOK/256 == 32
    const int ntile = swz >> 5;

    const size_t blockM = (size_t)mtile * 256;
    const int    colc   = ntile * 256;   // chunk-local col base

    const unsigned short* Ag = A  + blockM * K_IN;
    const unsigned short* Bg = Bt + (size_t)colc * K_IN;

    // --- staging roles: 4 lanes/row (16B each), 16 rows per wave-load
    const int r_in = l >> 2;                 // 0..15
    const int cch  = l & 3;                  // physical chunk
    const int kcs  = cch ^ ((r_in >> 1) & 3);// logical chunk to gather (inv swz)

    int g_off[2];
#pragma unroll
    for (int q = 0; q < 2; q++)
        g_off[q] = (w * 32 + q * 16 + r_in) * K_IN + kcs * 8;

#define STAGE(tt)                                                              \
    do {                                                                       \
        const int    _bb = (tt) & 3;                                           \
        const size_t _ko = (size_t)(tt) * 32;                                  \
        _Pragma("unroll")                                                      \
        for (int q = 0; q < 2; q++)                                            \
            GLOAD16(Ag + g_off[q] + _ko, &lds[_bb][0][(w * 32 + q * 16) * 32]);\
        _Pragma("unroll")                                                      \
        for (int q = 0; q < 2; q++)                                            \
            GLOAD16(Bg + g_off[q] + _ko, &lds[_bb][1][(w * 32 + q * 16) * 32]);\
    } while (0)

    // --- compute roles
    const int lrow = l & 15;
    const int kc   = l >> 4;                 // 0..3 (16B k-chunk)
    const int kswz = (lrow >> 1) & 3;
    const int pch  = (kc ^ kswz) * 8;        // physical chunk elem offset

    int aoff[8], boff[4];
#pragma unroll
    for (int mi = 0; mi < 8; mi++)
        aoff[mi] = (wm * 128 + mi * 16 + lrow) * 32 + pch;
#pragma unroll
    for (int ni = 0; ni < 4; ni++)
        boff[ni] = (wn * 64 + ni * 16 + lrow) * 32 + pch;

    f32x4 acc[8][4];
#pragma unroll
    for (int i = 0; i < 8; i++)
#pragma unroll
        for (int j = 0; j < 4; j++) acc[i][j] = (f32x4){0.f, 0.f, 0.f, 0.f};

    s16x8 F0a[8], F0b[4], F1a[8], F1b[4];

// One pipeline step: cur frags (Fca,Fcb) hold tile t_; optionally stage
// tile t_+3 and read tile t_+1 into (Fna,Fnb); then MFMA cur.
#define PIPE_STEP(t_, VM_, DO_STAGE_, DO_READ_, Fca, Fcb, Fna, Fnb)            \
    do {                                                                       \
        asm volatile("s_waitcnt vmcnt(" #VM_ ")" ::: "memory");                \
        __builtin_amdgcn_s_barrier();                                          \
        __builtin_amdgcn_sched_barrier(0);                                     \
        if (DO_STAGE_) STAGE((t_) + 3);                                        \
        if (DO_READ_) {                                                        \
            const unsigned short* Ab_ = &lds[((t_) + 1) & 3][0][0];            \
            const unsigned short* Bb_ = &lds[((t_) + 1) & 3][1][0];            \
            _Pragma("unroll")                                                  \
            for (int mi = 0; mi < 8; mi++)                                     \
                Fna[mi] = *(const s16x8*)&Ab_[aoff[mi]];                       \
            _Pragma("unroll")                                                  \
            for (int ni = 0; ni < 4; ni++)                                     \
                Fnb[ni] = *(const s16x8*)&Bb_[boff[ni]];                       \
        }                                                                      \
        __builtin_amdgcn_s_setprio(1);                                         \
        _Pragma("unroll")                                                      \
        for (int mi = 0; mi < 8; mi++)                                         \
            _Pragma("unroll")                                                  \
            for (int ni = 0; ni < 4; ni++)                                     \
                acc[mi][ni] = __builtin_amdgcn_mfma_f32_16x16x32_bf16(         \
                    __builtin_bit_cast(bf16x8, Fca[mi]),                       \
                    __builtin_bit_cast(bf16x8, Fcb[ni]),                       \
                    acc[mi][ni], 0, 0, 0);                                     \
        __builtin_amdgcn_s_setprio(0);                                         \
    } while (0)

    // NT = 128 tiles of BK=32.
    STAGE(0); STAGE(1); STAGE(2);                    // 12 loads in flight
    asm volatile("s_waitcnt vmcnt(8)" ::: "memory"); // tile 0 resident
    __builtin_amdgcn_s_barrier();
    __builtin_amdgcn_sched_barrier(0);
    {   // prologue read: F0 <- tile 0
        const unsigned short* Ab_ = &lds[0][0][0];
        const unsigned short* Bb_ = &lds[0][1][0];
#pragma unroll
        for (int mi = 0; mi < 8; mi++) F0a[mi] = *(const s16x8*)&Ab_[aoff[mi]];
#pragma unroll
        for (int ni = 0; ni < 4; ni++) F0b[ni] = *(const s16x8*)&Bb_[boff[ni]];
    }

    for (int t = 0; t < 124; t += 2) {
        PIPE_STEP(t,     4, true,  true, F0a, F0b, F1a, F1b);
        PIPE_STEP(t + 1, 4, true,  true, F1a, F1b, F0a, F0b);
    }
    PIPE_STEP(124, 4, true,  true, F0a, F0b, F1a, F1b);  // stages 127, reads 125
    PIPE_STEP(125, 4, false, true, F1a, F1b, F0a, F0b);  // reads 126
    PIPE_STEP(126, 0, false, true, F0a, F0b, F1a, F1b);  // reads 127
    // final tile 127
    __builtin_amdgcn_s_setprio(1);
#pragma unroll
    for (int mi = 0; mi < 8; mi++)
#pragma unroll
        for (int ni = 0; ni < 4; ni++)
            acc[mi][ni] = __builtin_amdgcn_mfma_f32_16x16x32_bf16(
                __builtin_bit_cast(bf16x8, F1a[mi]),
                __builtin_bit_cast(bf16x8, F1b[ni]),
                acc[mi][ni], 0, 0, 0);
    __builtin_amdgcn_s_setprio(0);
#undef PIPE_STEP
#undef STAGE

    // Epilogue: C/D layout col = lane&15, row = (lane>>4)*4 + reg (m89)
#pragma unroll
    for (int ni = 0; ni < 4; ++ni) {
        const int ng = n_base + colc + wn * 64 + ni * 16 + lrow;
        const float bv = bias[ng];
#pragma unroll
        for (int mi = 0; mi < 8; ++mi) {
            f32x4 v = acc[mi][ni];
#pragma unroll
            for (int r = 0; r < 4; r++) {
                const size_t grow = blockM + wm * 128 + mi * 16 + kc * 4 + r;
                C[grow * N_OUT + ng] = v[r] + bv;
            }
        }
    }
}

// ---------------------------------------------------------------------------
// Fallback: fully fused kernel (passed round 4, verbatim).
// ---------------------------------------------------------------------------
__global__ __launch_bounds__(256) void fused_w4a16_kernel(
    const float*        __restrict__ A,
    const unsigned int* __restrict__ qw,
    const unsigned int* __restrict__ qz,
    const float*        __restrict__ sc,
    const float*        __restrict__ bias,
    float*              __restrict__ C)
{
    __shared__ __align__(16) unsigned short As[128 * 64];
    __shared__ __align__(16) unsigned short Bs[128 * 64];

    const int tid = threadIdx.x;
    const int l   = tid & 63;
    const int w   = tid >> 6;
    const int wm  = w >> 1;
    const int wn  = w & 1;
    const size_t blockM = (size_t)blockIdx.x * 128;
    const int    colN   = blockIdx.y * 128;

    const float* Ag = A + blockM * K_IN;

    const int r_in = l >> 3;
    const int cch  = l & 7;
    int    aw_off[4];
    size_t ag_off[4];
#pragma unroll
    for (int qq = 0; qq < 4; qq++) {
        const int row = w * 32 + qq * 8 + r_in;
        aw_off[qq] = row * 64 + ((cch ^ r_in) * 8);
        ag_off[qq] = (size_t)row * K_IN + cch * 8;
    }

    const int kc = tid & 7;
    int ngl[4], j8[4], shn[4], bs_off[4];
#pragma unroll
    for (int p = 0; p < 4; p++) {
        const int nl = p * 32 + (tid >> 3);
        const int ng = colN + nl;
        ngl[p]    = ng;
        j8[p]     = ng >> 3;
        shn[p]    = 4 * (ng & 7);
        bs_off[p] = nl * 64 + ((kc ^ (nl & 7)) * 8);
    }

    f32x4 acc[4][4];
#pragma unroll
    for (int i = 0; i < 4; i++)
#pragma unroll
        for (int j = 0; j < 4; j++) acc[i][j] = (f32x4){0.f, 0.f, 0.f, 0.f};

    const int lrow = l & 15;
    const int lk   = l >> 4;
    const int NT   = K_IN / 64;

    for (int kt = 0; kt < NT; ++kt) {
        const int K0 = kt * 64;
        const int g  = K0 >> 7;

        float4 fa[4][2];
#pragma unroll
        for (int qq = 0; qq < 4; qq++) {
            fa[qq][0] = *(const float4*)(Ag + ag_off[qq] + K0);
            fa[qq][1] = *(const float4*)(Ag + ag_off[qq] + K0 + 4);
        }

        unsigned int q[4][8];
        float sf[4], nzs[4];
#pragma unroll
        for (int p = 0; p < 4; p++) {
            const unsigned int* qp = qw + (size_t)(K0 + kc * 8) * NP8 + j8[p];
#pragma unroll
            for (int i = 0; i < 8; i++) q[p][i] = qp[(size_t)i * NP8];
            const float zf = (float)((qz[(size_t)g * NP8 + j8[p]] >> shn[p]) & 0xFu);
            sf[p]  = sc[(size_t)g * N_OUT + ngl[p]];
            nzs[p] = -zf * sf[p];
        }

        __syncthreads();

#pragma unroll
        for (int qq = 0; qq < 4; qq++) {
            bf16x8 h;
#pragma unroll
            for (int i = 0; i < 4; i++) {
                h[i]     = (__bf16)(((const float*)&fa[qq][0])[i]);
                h[i + 4] = (__bf16)(((const float*)&fa[qq][1])[i]);
            }
            *(int4*)&As[aw_off[qq]] = __builtin_bit_cast(int4, h);
        }
#pragma unroll
        for (int p = 0; p < 4; p++) {
            bf16x8 h;
#pragma unroll
            for (int i = 0; i < 8; i++) {
                const float nib = (float)((q[p][i] >> shn[p]) & 0xFu);
                h[i] = (__bf16)fmaf(nib, sf[p], nzs[p]);
            }
            *(int4*)&Bs[bs_off[p]] = __builtin_bit_cast(int4, h);
        }

        __syncthreads();

#pragma unroll
        for (int ks = 0; ks < 2; ++ks) {
            s16x8 a[4], b[4];
            const int kcc = ks * 4 + lk;
#pragma unroll
            for (int mi = 0; mi < 4; mi++) {
                const int row = wm * 64 + mi * 16 + lrow;
                a[mi] = *(const s16x8*)&As[row * 64 + ((kcc ^ (row & 7)) * 8)];
            }
#pragma unroll
            for (int ni = 0; ni < 4; ni++) {
                const int row = wn * 64 + ni * 16 + lrow;
                b[ni] = *(const s16x8*)&Bs[row * 64 + ((kcc ^ (row & 7)) * 8)];
            }
#pragma unroll
            for (int mi = 0; mi < 4; mi++)
#pragma unroll
                for (int ni = 0; ni < 4; ni++)
                    acc[mi][ni] = __builtin_amdgcn_mfma_f32_16x16x32_bf16(
                        __builtin_bit_cast(bf16x8, a[mi]),
                        __builtin_bit_cast(bf16x8, b[ni]),
                        acc[mi][ni], 0, 0, 0);
        }
    }

#pragma unroll
    for (int ni = 0; ni < 4; ++ni) {
        const int ng = colN + wn * 64 + ni * 16 + lrow;
        const float bv = bias[ng];
#pragma unroll
        for (int mi = 0; mi < 4; ++mi) {
            f32x4 v = acc[mi][ni];
#pragma unroll
            for (int r = 0; r < 4; r++) {
                const size_t grow = blockM + wm * 64 + mi * 16 + lk * 4 + r;
                C[grow * N_OUT + ng] = v[r] + bv;
            }
        }
    }
}

// ---------------------------------------------------------------------------
extern "C" void kernel_launch(void* const* d_in, const int* in_sizes, int n_in,
                              void* d_out, int out_size, void* d_ws, size_t ws_size,
                              hipStream_t stream)
{
    const float*        x    = (const float*)d_in[0];
    const unsigned int* qw   = (const unsigned int*)d_in[1];
    const unsigned int* qz   = (const unsigned int*)d_in[2];
    const float*        sc   = (const float*)d_in[3];
    const float*        bias = (const float*)d_in[4];
    float*              out  = (float*)d_out;

    const size_t XBF    = (size_t)M_TOK * K_IN * 2;   // 64 MiB bf16 x
    const size_t COL256 = (size_t)256 * K_IN * 2;     // 2 MiB per 256 cols of W^T

    if (ws_size >= XBF + COL256) {
        // Tier A (proven firing r6-r9): convert x once, chunked dequant +
        // 256x256 register-pipelined gemm.
        unsigned short* xb = (unsigned short*)d_ws;
        unsigned short* wt = (unsigned short*)((char*)d_ws + XBF);
        const long n8 = (long)M_TOK * K_IN / 8;
        convert_x_kernel<<<2048, 256, 0, stream>>>(x, xb, n8);

        size_t chunk_cols = ((ws_size - XBF) / COL256) * 256;
        if (chunk_cols > (size_t)N_OUT) chunk_cols = N_OUT;
        for (int n0 = 0; n0 < N_OUT; n0 += (int)chunk_cols) {
            int nc = N_OUT - n0;
            if (nc > (int)chunk_cols) nc = (int)chunk_cols;
            dequant_kernel<<<dim3(K_IN / GS, nc / 128), 256, 0, stream>>>(qw, qz, sc, wt, n0);
            gemm_256_kernel<<<32 * (nc / 256), 512, 0, stream>>>(xb, wt, bias, out, n0);
        }
    } else {
        // Fallback: fully fused (proven round 4).
        fused_w4a16_kernel<<<dim3(M_TOK / 128, N_OUT / 128), 256, 0, stream>>>(
            x, qw, qz, sc, bias, out);
    }
}